// Round 4
// baseline (217.684 us; speedup 1.0000x reference)
//
#include <hip/hip_runtime.h>

#define NN 50000
#define DD 128

typedef __attribute__((ext_vector_type(8))) short bf16x8;
typedef __attribute__((ext_vector_type(4))) float f32x4;

static __device__ __forceinline__ unsigned short f2bf(float x) {
    unsigned int u = __float_as_uint(x);
    unsigned int r = (u + 0x7fffu + ((u >> 16) & 1u)) >> 16;
    return (unsigned short)r;
}

// XOR-swizzle for 256B-row LDS tiles (row = byte>>8): spreads stride-256B
// column reads across 8 distinct 16B slots -> 2-way max (free).
static __device__ __forceinline__ int swz(int byte) {
    return byte ^ (((byte >> 8) & 7) << 4);
}

// ---------- hist + one-time Wt build (W[k][j] f32 -> Wt[j][k] bf16) ----------
__global__ void __launch_bounds__(256) hist_wt_kernel(
    const int* __restrict__ row, int* __restrict__ counts, int E,
    const float* __restrict__ W, unsigned short* __restrict__ Wt)
{
    if (blockIdx.x == 0) {
        for (int idx = threadIdx.x; idx < DD * DD; idx += 256) {
            int k = idx >> 7;
            int j = idx & 127;
            Wt[j * DD + k] = f2bf(W[idx]);
        }
    }
    int i = blockIdx.x * 256 + threadIdx.x;
    int stride = gridDim.x * 256;
    for (int e = i; e < E; e += stride) atomicAdd(&counts[row[e]], 1);
}

// ---------- single-launch exclusive scan (1 block, 1024 threads) ----------
#define CHUNK 49   // 1024*49 = 50176 >= 50000
__global__ void __launch_bounds__(1024) scan_kernel(
    const int* __restrict__ counts, int* __restrict__ wptr)
{
    __shared__ int s[1024];
    int tid = threadIdx.x;
    int base = tid * CHUNK;
    int sum = 0;
    #pragma unroll 7
    for (int i = 0; i < CHUNK; ++i) {
        int idx = base + i;
        if (idx < NN) sum += counts[idx];
    }
    s[tid] = sum;
    __syncthreads();
    #pragma unroll
    for (int d = 1; d < 1024; d <<= 1) {
        int t = (tid >= d) ? s[tid - d] : 0;
        __syncthreads();
        s[tid] += t;
        __syncthreads();
    }
    int run = s[tid] - sum;   // exclusive prefix
    #pragma unroll 7
    for (int i = 0; i < CHUNK; ++i) {
        int idx = base + i;
        if (idx < NN) { wptr[idx] = run; run += counts[idx]; }
    }
}

// after this, wptr[r] == segment end (start = end - counts[r])
__global__ void __launch_bounds__(256) edge_scatter_kernel(
    const int* __restrict__ row, const int* __restrict__ col,
    int* __restrict__ wptr, unsigned short* __restrict__ edge_col, int E)
{
    int i = blockIdx.x * 256 + threadIdx.x;
    int stride = gridDim.x * 256;
    for (int e = i; e < E; e += stride) {
        int r = row[e];
        int pos = atomicAdd(&wptr[r], 1);
        edge_col[pos] = (unsigned short)col[e];
    }
}

// ---------- y = bf16(x @ W): 64 rows/block, 4 waves, swizzled LDS ----------
__global__ void __launch_bounds__(256) gemm_xw_kernel(
    const float* __restrict__ x,
    const unsigned short* __restrict__ Wt,    // [j][k] bf16
    unsigned short* __restrict__ y)           // [NN][DD] bf16
{
    __shared__ unsigned short w_lds[DD * DD]; // 32KB, swizzled [j][k]
    __shared__ unsigned short a_lds[64 * DD]; // 16KB, swizzled [r][k]

    const int tid = threadIdx.x;
    const int i0 = blockIdx.x * 64;

    // stage Wt (2048 uint4); row j = idx>>4
    {
        const uint4* src = reinterpret_cast<const uint4*>(Wt);
        #pragma unroll
        for (int it = 0; it < 8; ++it) {
            int idx = tid + it * 256;
            uint4 v = src[idx];
            *reinterpret_cast<uint4*>((char*)w_lds + swz(idx * 16)) = v;
        }
    }
    // stage x rows -> bf16 (2048 float4 reads); row r = idx>>5
    #pragma unroll
    for (int it = 0; it < 8; ++it) {
        int idx = tid + it * 256;
        int r = idx >> 5;
        int c4 = idx & 31;
        int grow = i0 + r;
        float4 v = make_float4(0.f, 0.f, 0.f, 0.f);
        if (grow < NN) v = reinterpret_cast<const float4*>(x + (size_t)grow * DD)[c4];
        ushort4 o;
        o.x = f2bf(v.x); o.y = f2bf(v.y); o.z = f2bf(v.z); o.w = f2bf(v.w);
        *reinterpret_cast<ushort4*>((char*)a_lds + swz(r * 256 + c4 * 8)) = o;
    }
    __syncthreads();

    const int wave = tid >> 6;
    const int l64 = tid & 63;
    const int lrow = l64 & 15;
    const int kgrp = l64 >> 4;

    bf16x8 afrag[4];
    #pragma unroll
    for (int s = 0; s < 4; ++s) {
        int byte = (wave * 16 + lrow) * 256 + (s * 32 + kgrp * 8) * 2;
        afrag[s] = *reinterpret_cast<const bf16x8*>((char*)a_lds + swz(byte));
    }

    f32x4 acc[8];
    #pragma unroll
    for (int t = 0; t < 8; ++t) acc[t] = (f32x4){0.f, 0.f, 0.f, 0.f};

    #pragma unroll
    for (int t = 0; t < 8; ++t) {
        #pragma unroll
        for (int s = 0; s < 4; ++s) {
            int byte = (t * 16 + lrow) * 256 + (s * 32 + kgrp * 8) * 2;
            bf16x8 bfrag = *reinterpret_cast<const bf16x8*>((char*)w_lds + swz(byte));
            acc[t] = __builtin_amdgcn_mfma_f32_16x16x32_bf16(afrag[s], bfrag, acc[t], 0, 0, 0);
        }
    }
    __syncthreads();   // a_lds fragment reads done; reuse for output repack

    // D layout: col = lane&15, row = (lane>>4)*4 + reg  [m89-verified]
    #pragma unroll
    for (int t = 0; t < 8; ++t) {
        #pragma unroll
        for (int r = 0; r < 4; ++r) {
            int lr = wave * 16 + kgrp * 4 + r;
            int byte = lr * 256 + (t * 16 + lrow) * 2;
            *reinterpret_cast<unsigned short*>((char*)a_lds + swz(byte)) = f2bf(acc[t][r]);
        }
    }
    __syncthreads();

    // coalesced bf16 store: 1024 uint4
    {
        uint4* dst = reinterpret_cast<uint4*>(y) + (size_t)i0 * 16;
        #pragma unroll
        for (int it = 0; it < 4; ++it) {
            int idx = tid + it * 256;
            if (i0 + (idx >> 4) < NN) {
                uint4 v = *reinterpret_cast<const uint4*>((char*)a_lds + swz(idx * 16));
                dst[idx] = v;
            }
        }
    }
}

// ---------- gather from y + mean + bias + ReLU -> out (no LDS) ----------
__global__ void __launch_bounds__(256) gather_out_kernel(
    const unsigned short* __restrict__ y,
    const int* __restrict__ wptr, const int* __restrict__ counts,
    const unsigned short* __restrict__ edge_col,
    const float* __restrict__ bias,
    float* __restrict__ out)
{
    int node = blockIdx.x * 8 + (threadIdx.x >> 5);
    int lane = threadIdx.x & 31;
    float4 bb = reinterpret_cast<const float4*>(bias)[lane];
    if (node >= NN) return;
    int cnt = counts[node];
    int end = wptr[node];
    int start = end - cnt;
    float4 acc = make_float4(0.f, 0.f, 0.f, 0.f);
    for (int base = start; base < end; base += 32) {
        int cl = (base + lane < end) ? (int)edge_col[base + lane] : 0;
        int m = min(32, end - base);
        #pragma unroll 2
        for (int ii = 0; ii < m; ++ii) {
            int c = __shfl(cl, ii, 32);
            uint2 u = reinterpret_cast<const uint2*>(y + (size_t)c * DD)[lane];
            acc.x += __uint_as_float(u.x << 16);
            acc.y += __uint_as_float(u.x & 0xffff0000u);
            acc.z += __uint_as_float(u.y << 16);
            acc.w += __uint_as_float(u.y & 0xffff0000u);
        }
    }
    float inv = 1.0f / fmaxf((float)cnt, 1.0f);
    float4 o;
    o.x = fmaxf(acc.x * inv + bb.x, 0.f);
    o.y = fmaxf(acc.y * inv + bb.y, 0.f);
    o.z = fmaxf(acc.z * inv + bb.z, 0.f);
    o.w = fmaxf(acc.w * inv + bb.w, 0.f);
    reinterpret_cast<float4*>(out + (size_t)node * DD)[lane] = o;
}

// ---------- fallback path (ws too small): atomic scatter + f32-staged gemm ----------
__global__ void __launch_bounds__(256) wt_only_kernel(
    const float* __restrict__ W, unsigned short* __restrict__ Wt)
{
    for (int idx = threadIdx.x; idx < DD * DD; idx += 256) {
        int k = idx >> 7;
        int j = idx & 127;
        Wt[j * DD + k] = f2bf(W[idx]);
    }
}

__global__ void __launch_bounds__(256) scatter_atomic_kernel(
    const float* __restrict__ x,
    const int* __restrict__ row, const int* __restrict__ col,
    float* __restrict__ agg, int* __restrict__ counts, int E)
{
    int gid = blockIdx.x * blockDim.x + threadIdx.x;
    int group = gid >> 5;
    int lane = threadIdx.x & 31;
    int ngroups = (gridDim.x * blockDim.x) >> 5;
    for (int e = group; e < E; e += ngroups) {
        int r = row[e];
        int c = col[e];
        float4 v = reinterpret_cast<const float4*>(x + (size_t)c * DD)[lane];
        float* dst = agg + (size_t)r * DD + lane * 4;
        unsafeAtomicAdd(dst + 0, v.x);
        unsafeAtomicAdd(dst + 1, v.y);
        unsafeAtomicAdd(dst + 2, v.z);
        unsafeAtomicAdd(dst + 3, v.w);
        if (lane == 0) atomicAdd(counts + r, 1);
    }
}

__global__ void __launch_bounds__(256) gemm_fb_kernel(
    const float* __restrict__ agg,
    const int* __restrict__ counts,
    const unsigned short* __restrict__ Wt,
    const float* __restrict__ bias,
    float* __restrict__ out)
{
    __shared__ unsigned short w_lds[DD * DD];
    __shared__ unsigned short a_lds[64 * DD];
    __shared__ float b_lds[DD];

    const int tid = threadIdx.x;
    const int i0 = blockIdx.x * 64;

    {
        const uint4* src = reinterpret_cast<const uint4*>(Wt);
        #pragma unroll
        for (int it = 0; it < 8; ++it) {
            int idx = tid + it * 256;
            *reinterpret_cast<uint4*>((char*)w_lds + swz(idx * 16)) = src[idx];
        }
    }
    if (tid < DD) b_lds[tid] = bias[tid];

    #pragma unroll
    for (int it = 0; it < 8; ++it) {
        int idx = tid + it * 256;
        int r = idx >> 5;
        int c4 = idx & 31;
        int grow = i0 + r;
        float4 v = make_float4(0.f, 0.f, 0.f, 0.f);
        float inv = 0.f;
        if (grow < NN) {
            v = reinterpret_cast<const float4*>(agg + (size_t)grow * DD)[c4];
            inv = 1.0f / fmaxf((float)counts[grow], 1.0f);
        }
        ushort4 o;
        o.x = f2bf(v.x * inv); o.y = f2bf(v.y * inv);
        o.z = f2bf(v.z * inv); o.w = f2bf(v.w * inv);
        *reinterpret_cast<ushort4*>((char*)a_lds + swz(r * 256 + c4 * 8)) = o;
    }
    __syncthreads();

    const int wave = tid >> 6;
    const int l64 = tid & 63;
    const int lrow = l64 & 15;
    const int kgrp = l64 >> 4;

    bf16x8 afrag[4];
    #pragma unroll
    for (int s = 0; s < 4; ++s) {
        int byte = (wave * 16 + lrow) * 256 + (s * 32 + kgrp * 8) * 2;
        afrag[s] = *reinterpret_cast<const bf16x8*>((char*)a_lds + swz(byte));
    }

    f32x4 acc[8];
    #pragma unroll
    for (int t = 0; t < 8; ++t) acc[t] = (f32x4){0.f, 0.f, 0.f, 0.f};

    #pragma unroll
    for (int t = 0; t < 8; ++t) {
        #pragma unroll
        for (int s = 0; s < 4; ++s) {
            int byte = (t * 16 + lrow) * 256 + (s * 32 + kgrp * 8) * 2;
            bf16x8 bfrag = *reinterpret_cast<const bf16x8*>((char*)w_lds + swz(byte));
            acc[t] = __builtin_amdgcn_mfma_f32_16x16x32_bf16(afrag[s], bfrag, acc[t], 0, 0, 0);
        }
    }

    #pragma unroll
    for (int t = 0; t < 8; ++t) {
        int colj = t * 16 + lrow;
        float bbv = b_lds[colj];
        #pragma unroll
        for (int r = 0; r < 4; ++r) {
            int grow = i0 + wave * 16 + kgrp * 4 + r;
            if (grow < NN) {
                out[(size_t)grow * DD + colj] = fmaxf(acc[t][r] + bbv, 0.f);
            }
        }
    }
}

extern "C" void kernel_launch(void* const* d_in, const int* in_sizes, int n_in,
                              void* d_out, int out_size, void* d_ws, size_t ws_size,
                              hipStream_t stream) {
    const float* x  = (const float*)d_in[0];
    const int* ei   = (const int*)d_in[1];
    const float* W  = (const float*)d_in[2];
    const float* b  = (const float*)d_in[3];
    float* out      = (float*)d_out;

    const int E = in_sizes[1] / 2;
    const int* row = ei;
    const int* col = ei + E;

    // ws layout (16B-aligned)
    char* wsc = (char*)d_ws;
    int* counts              = (int*)(wsc + 0);            // 200704 B
    int* wptr                = (int*)(wsc + 200704);       // 200704 B
    unsigned short* edge_col = (unsigned short*)(wsc + 401408);  // 1280000 B
    unsigned short* Wt       = (unsigned short*)(wsc + 1681408); // 32768 B
    unsigned short* y        = (unsigned short*)(wsc + 1714176); // 12800000 B
    const size_t WS_NEED = 14514176;

    if (ws_size >= WS_NEED) {
        hipMemsetAsync(counts, 0, (size_t)NN * sizeof(int), stream);
        hist_wt_kernel<<<2500, 256, 0, stream>>>(row, counts, E, W, Wt);
        gemm_xw_kernel<<<(NN + 63) / 64, 256, 0, stream>>>(x, Wt, y);
        scan_kernel<<<1, 1024, 0, stream>>>(counts, wptr);
        edge_scatter_kernel<<<2500, 256, 0, stream>>>(row, col, wptr, edge_col, E);
        gather_out_kernel<<<(NN + 7) / 8, 256, 0, stream>>>(y, wptr, counts, edge_col, b, out);
    } else {
        int* fc = (int*)d_ws;
        unsigned short* fWt = (unsigned short*)(wsc + 200704);
        hipMemsetAsync(d_out, 0, (size_t)NN * DD * sizeof(float), stream);
        hipMemsetAsync(fc, 0, (size_t)NN * sizeof(int), stream);
        wt_only_kernel<<<1, 256, 0, stream>>>(W, fWt);
        scatter_atomic_kernel<<<2048, 256, 0, stream>>>(x, row, col, out, fc, E);
        gemm_fb_kernel<<<(NN + 63) / 64, 256, 0, stream>>>(out, fc, fWt, b, out);
    }
}

// Round 5
// 138.101 us; speedup vs baseline: 1.5763x; 1.5763x over previous
//
#include <hip/hip_runtime.h>

#define NN 50000
#define DD 128
#define NB 196          // ceil(50000/256)

typedef __attribute__((ext_vector_type(8))) short bf16x8;
typedef __attribute__((ext_vector_type(4))) float f32x4;

static __device__ __forceinline__ unsigned short f2bf(float x) {
    unsigned int u = __float_as_uint(x);
    unsigned int r = (u + 0x7fffu + ((u >> 16) & 1u)) >> 16;
    return (unsigned short)r;
}

// XOR-swizzle for 256B-row LDS tiles (row = byte>>8): spreads stride-256B
// column reads across 8 distinct 16B slots -> 2-way max (free).
static __device__ __forceinline__ int swz(int byte) {
    return byte ^ (((byte >> 8) & 7) << 4);
}

// ---------- hist + one-time Wt build (W[k][j] f32 -> Wt[j][k] bf16) ----------
__global__ void __launch_bounds__(256) hist_wt_kernel(
    const int* __restrict__ row, int* __restrict__ counts, int E,
    const float* __restrict__ W, unsigned short* __restrict__ Wt)
{
    if (blockIdx.x == 0) {
        for (int idx = threadIdx.x; idx < DD * DD; idx += 256) {
            int k = idx >> 7;
            int j = idx & 127;
            Wt[j * DD + k] = f2bf(W[idx]);
        }
    }
    int i = blockIdx.x * 256 + threadIdx.x;
    int stride = gridDim.x * 256;
    for (int e = i; e < E; e += stride) atomicAdd(&counts[row[e]], 1);
}

// ---------- hierarchical scan: per-chunk exclusive scan + block sums ----------
__global__ void __launch_bounds__(256) scan_local_kernel(
    const int* __restrict__ counts, int* __restrict__ wptr, int* __restrict__ bsum)
{
    __shared__ int s[256];
    int tid = threadIdx.x;
    int i = blockIdx.x * 256 + tid;
    int v = (i < NN) ? counts[i] : 0;
    s[tid] = v;
    __syncthreads();
    #pragma unroll
    for (int d = 1; d < 256; d <<= 1) {
        int t = (tid >= d) ? s[tid - d] : 0;
        __syncthreads();
        s[tid] += t;
        __syncthreads();
    }
    if (i < NN) wptr[i] = s[tid] - v;        // exclusive within chunk
    if (tid == 255) bsum[blockIdx.x] = s[255];
}

// each block reduces bsum[0..blockIdx) and adds the prefix to its wptr chunk
__global__ void __launch_bounds__(256) scan_merge_add_kernel(
    int* __restrict__ wptr, const int* __restrict__ bsum)
{
    __shared__ int s[256];
    int tid = threadIdx.x;
    int b = blockIdx.x;
    s[tid] = (tid < b && tid < NB) ? bsum[tid] : 0;
    __syncthreads();
    #pragma unroll
    for (int d = 128; d > 0; d >>= 1) {
        if (tid < d) s[tid] += s[tid + d];
        __syncthreads();
    }
    int prefix = s[0];
    int i = b * 256 + tid;
    if (i < NN) wptr[i] += prefix;
}

// after this, wptr[r] == segment end (start = end - counts[r])
__global__ void __launch_bounds__(256) edge_scatter_kernel(
    const int* __restrict__ row, const int* __restrict__ col,
    int* __restrict__ wptr, unsigned short* __restrict__ edge_col, int E)
{
    int i = blockIdx.x * 256 + threadIdx.x;
    int stride = gridDim.x * 256;
    for (int e = i; e < E; e += stride) {
        int r = row[e];
        int pos = atomicAdd(&wptr[r], 1);
        edge_col[pos] = (unsigned short)col[e];
    }
}

// ---------- y = bf16(x @ W): 64 rows/block, 4 waves, swizzled LDS ----------
__global__ void __launch_bounds__(256) gemm_xw_kernel(
    const float* __restrict__ x,
    const unsigned short* __restrict__ Wt,    // [j][k] bf16
    unsigned short* __restrict__ y)           // [NN][DD] bf16
{
    __shared__ unsigned short w_lds[DD * DD]; // 32KB, swizzled [j][k]
    __shared__ unsigned short a_lds[64 * DD]; // 16KB, swizzled [r][k]

    const int tid = threadIdx.x;
    const int i0 = blockIdx.x * 64;

    // stage Wt (2048 uint4); row j = idx>>4
    {
        const uint4* src = reinterpret_cast<const uint4*>(Wt);
        #pragma unroll
        for (int it = 0; it < 8; ++it) {
            int idx = tid + it * 256;
            uint4 v = src[idx];
            *reinterpret_cast<uint4*>((char*)w_lds + swz(idx * 16)) = v;
        }
    }
    // stage x rows -> bf16 (2048 float4 reads); row r = idx>>5
    #pragma unroll
    for (int it = 0; it < 8; ++it) {
        int idx = tid + it * 256;
        int r = idx >> 5;
        int c4 = idx & 31;
        int grow = i0 + r;
        float4 v = make_float4(0.f, 0.f, 0.f, 0.f);
        if (grow < NN) v = reinterpret_cast<const float4*>(x + (size_t)grow * DD)[c4];
        ushort4 o;
        o.x = f2bf(v.x); o.y = f2bf(v.y); o.z = f2bf(v.z); o.w = f2bf(v.w);
        *reinterpret_cast<ushort4*>((char*)a_lds + swz(r * 256 + c4 * 8)) = o;
    }
    __syncthreads();

    const int wave = tid >> 6;
    const int l64 = tid & 63;
    const int lrow = l64 & 15;
    const int kgrp = l64 >> 4;

    bf16x8 afrag[4];
    #pragma unroll
    for (int s = 0; s < 4; ++s) {
        int byte = (wave * 16 + lrow) * 256 + (s * 32 + kgrp * 8) * 2;
        afrag[s] = *reinterpret_cast<const bf16x8*>((char*)a_lds + swz(byte));
    }

    f32x4 acc[8];
    #pragma unroll
    for (int t = 0; t < 8; ++t) acc[t] = (f32x4){0.f, 0.f, 0.f, 0.f};

    #pragma unroll
    for (int t = 0; t < 8; ++t) {
        #pragma unroll
        for (int s = 0; s < 4; ++s) {
            int byte = (t * 16 + lrow) * 256 + (s * 32 + kgrp * 8) * 2;
            bf16x8 bfrag = *reinterpret_cast<const bf16x8*>((char*)w_lds + swz(byte));
            acc[t] = __builtin_amdgcn_mfma_f32_16x16x32_bf16(afrag[s], bfrag, acc[t], 0, 0, 0);
        }
    }
    __syncthreads();   // a_lds fragment reads done; reuse for output repack

    // D layout: col = lane&15, row = (lane>>4)*4 + reg  [m89-verified]
    #pragma unroll
    for (int t = 0; t < 8; ++t) {
        #pragma unroll
        for (int r = 0; r < 4; ++r) {
            int lr = wave * 16 + kgrp * 4 + r;
            int byte = lr * 256 + (t * 16 + lrow) * 2;
            *reinterpret_cast<unsigned short*>((char*)a_lds + swz(byte)) = f2bf(acc[t][r]);
        }
    }
    __syncthreads();

    // coalesced bf16 store: 1024 uint4
    {
        uint4* dst = reinterpret_cast<uint4*>(y) + (size_t)i0 * 16;
        #pragma unroll
        for (int it = 0; it < 4; ++it) {
            int idx = tid + it * 256;
            if (i0 + (idx >> 4) < NN) {
                uint4 v = *reinterpret_cast<const uint4*>((char*)a_lds + swz(idx * 16));
                dst[idx] = v;
            }
        }
    }
}

// ---------- gather from y + mean + bias + ReLU -> out (no LDS) ----------
__global__ void __launch_bounds__(256) gather_out_kernel(
    const unsigned short* __restrict__ y,
    const int* __restrict__ wptr, const int* __restrict__ counts,
    const unsigned short* __restrict__ edge_col,
    const float* __restrict__ bias,
    float* __restrict__ out)
{
    int node = blockIdx.x * 8 + (threadIdx.x >> 5);
    int lane = threadIdx.x & 31;
    float4 bb = reinterpret_cast<const float4*>(bias)[lane];
    if (node >= NN) return;
    int cnt = counts[node];
    int end = wptr[node];
    int start = end - cnt;
    float4 acc = make_float4(0.f, 0.f, 0.f, 0.f);
    for (int base = start; base < end; base += 32) {
        int cl = (base + lane < end) ? (int)edge_col[base + lane] : 0;
        int m = min(32, end - base);
        #pragma unroll 2
        for (int ii = 0; ii < m; ++ii) {
            int c = __shfl(cl, ii, 32);
            uint2 u = reinterpret_cast<const uint2*>(y + (size_t)c * DD)[lane];
            acc.x += __uint_as_float(u.x << 16);
            acc.y += __uint_as_float(u.x & 0xffff0000u);
            acc.z += __uint_as_float(u.y << 16);
            acc.w += __uint_as_float(u.y & 0xffff0000u);
        }
    }
    float inv = 1.0f / fmaxf((float)cnt, 1.0f);
    float4 o;
    o.x = fmaxf(acc.x * inv + bb.x, 0.f);
    o.y = fmaxf(acc.y * inv + bb.y, 0.f);
    o.z = fmaxf(acc.z * inv + bb.z, 0.f);
    o.w = fmaxf(acc.w * inv + bb.w, 0.f);
    reinterpret_cast<float4*>(out + (size_t)node * DD)[lane] = o;
}

// ---------- fallback path (ws too small): atomic scatter + f32-staged gemm ----------
__global__ void __launch_bounds__(256) wt_only_kernel(
    const float* __restrict__ W, unsigned short* __restrict__ Wt)
{
    for (int idx = threadIdx.x; idx < DD * DD; idx += 256) {
        int k = idx >> 7;
        int j = idx & 127;
        Wt[j * DD + k] = f2bf(W[idx]);
    }
}

__global__ void __launch_bounds__(256) scatter_atomic_kernel(
    const float* __restrict__ x,
    const int* __restrict__ row, const int* __restrict__ col,
    float* __restrict__ agg, int* __restrict__ counts, int E)
{
    int gid = blockIdx.x * blockDim.x + threadIdx.x;
    int group = gid >> 5;
    int lane = threadIdx.x & 31;
    int ngroups = (gridDim.x * blockDim.x) >> 5;
    for (int e = group; e < E; e += ngroups) {
        int r = row[e];
        int c = col[e];
        float4 v = reinterpret_cast<const float4*>(x + (size_t)c * DD)[lane];
        float* dst = agg + (size_t)r * DD + lane * 4;
        unsafeAtomicAdd(dst + 0, v.x);
        unsafeAtomicAdd(dst + 1, v.y);
        unsafeAtomicAdd(dst + 2, v.z);
        unsafeAtomicAdd(dst + 3, v.w);
        if (lane == 0) atomicAdd(counts + r, 1);
    }
}

__global__ void __launch_bounds__(256) gemm_fb_kernel(
    const float* __restrict__ agg,
    const int* __restrict__ counts,
    const unsigned short* __restrict__ Wt,
    const float* __restrict__ bias,
    float* __restrict__ out)
{
    __shared__ unsigned short w_lds[DD * DD];
    __shared__ unsigned short a_lds[64 * DD];
    __shared__ float b_lds[DD];

    const int tid = threadIdx.x;
    const int i0 = blockIdx.x * 64;

    {
        const uint4* src = reinterpret_cast<const uint4*>(Wt);
        #pragma unroll
        for (int it = 0; it < 8; ++it) {
            int idx = tid + it * 256;
            *reinterpret_cast<uint4*>((char*)w_lds + swz(idx * 16)) = src[idx];
        }
    }
    if (tid < DD) b_lds[tid] = bias[tid];

    #pragma unroll
    for (int it = 0; it < 8; ++it) {
        int idx = tid + it * 256;
        int r = idx >> 5;
        int c4 = idx & 31;
        int grow = i0 + r;
        float4 v = make_float4(0.f, 0.f, 0.f, 0.f);
        float inv = 0.f;
        if (grow < NN) {
            v = reinterpret_cast<const float4*>(agg + (size_t)grow * DD)[c4];
            inv = 1.0f / fmaxf((float)counts[grow], 1.0f);
        }
        ushort4 o;
        o.x = f2bf(v.x * inv); o.y = f2bf(v.y * inv);
        o.z = f2bf(v.z * inv); o.w = f2bf(v.w * inv);
        *reinterpret_cast<ushort4*>((char*)a_lds + swz(r * 256 + c4 * 8)) = o;
    }
    __syncthreads();

    const int wave = tid >> 6;
    const int l64 = tid & 63;
    const int lrow = l64 & 15;
    const int kgrp = l64 >> 4;

    bf16x8 afrag[4];
    #pragma unroll
    for (int s = 0; s < 4; ++s) {
        int byte = (wave * 16 + lrow) * 256 + (s * 32 + kgrp * 8) * 2;
        afrag[s] = *reinterpret_cast<const bf16x8*>((char*)a_lds + swz(byte));
    }

    f32x4 acc[8];
    #pragma unroll
    for (int t = 0; t < 8; ++t) acc[t] = (f32x4){0.f, 0.f, 0.f, 0.f};

    #pragma unroll
    for (int t = 0; t < 8; ++t) {
        #pragma unroll
        for (int s = 0; s < 4; ++s) {
            int byte = (t * 16 + lrow) * 256 + (s * 32 + kgrp * 8) * 2;
            bf16x8 bfrag = *reinterpret_cast<const bf16x8*>((char*)w_lds + swz(byte));
            acc[t] = __builtin_amdgcn_mfma_f32_16x16x32_bf16(afrag[s], bfrag, acc[t], 0, 0, 0);
        }
    }

    #pragma unroll
    for (int t = 0; t < 8; ++t) {
        int colj = t * 16 + lrow;
        float bbv = b_lds[colj];
        #pragma unroll
        for (int r = 0; r < 4; ++r) {
            int grow = i0 + wave * 16 + kgrp * 4 + r;
            if (grow < NN) {
                out[(size_t)grow * DD + colj] = fmaxf(acc[t][r] + bbv, 0.f);
            }
        }
    }
}

extern "C" void kernel_launch(void* const* d_in, const int* in_sizes, int n_in,
                              void* d_out, int out_size, void* d_ws, size_t ws_size,
                              hipStream_t stream) {
    const float* x  = (const float*)d_in[0];
    const int* ei   = (const int*)d_in[1];
    const float* W  = (const float*)d_in[2];
    const float* b  = (const float*)d_in[3];
    float* out      = (float*)d_out;

    const int E = in_sizes[1] / 2;
    const int* row = ei;
    const int* col = ei + E;

    // ws layout (16B-aligned)
    char* wsc = (char*)d_ws;
    int* counts              = (int*)(wsc + 0);            // 200704 B
    int* wptr                = (int*)(wsc + 200704);       // 200704 B
    int* bsum                = (int*)(wsc + 401408);       // 1024 B
    unsigned short* edge_col = (unsigned short*)(wsc + 402432);  // 1280000 B
    unsigned short* Wt       = (unsigned short*)(wsc + 1682432); // 32768 B
    unsigned short* y        = (unsigned short*)(wsc + 1715200); // 12800000 B
    const size_t WS_NEED = 14515200;

    if (ws_size >= WS_NEED) {
        hipMemsetAsync(counts, 0, (size_t)NN * sizeof(int), stream);
        hist_wt_kernel<<<2500, 256, 0, stream>>>(row, counts, E, W, Wt);
        gemm_xw_kernel<<<(NN + 63) / 64, 256, 0, stream>>>(x, Wt, y);
        scan_local_kernel<<<NB, 256, 0, stream>>>(counts, wptr, bsum);
        scan_merge_add_kernel<<<NB, 256, 0, stream>>>(wptr, bsum);
        edge_scatter_kernel<<<2500, 256, 0, stream>>>(row, col, wptr, edge_col, E);
        gather_out_kernel<<<(NN + 7) / 8, 256, 0, stream>>>(y, wptr, counts, edge_col, b, out);
    } else {
        int* fc = (int*)d_ws;
        unsigned short* fWt = (unsigned short*)(wsc + 200704);
        hipMemsetAsync(d_out, 0, (size_t)NN * DD * sizeof(float), stream);
        hipMemsetAsync(fc, 0, (size_t)NN * sizeof(int), stream);
        wt_only_kernel<<<1, 256, 0, stream>>>(W, fWt);
        scatter_atomic_kernel<<<2048, 256, 0, stream>>>(x, row, col, out, fc, E);
        gemm_fb_kernel<<<(NN + 63) / 64, 256, 0, stream>>>(out, fc, fWt, b, out);
    }
}

// Round 6
// 108.789 us; speedup vs baseline: 2.0010x; 1.2694x over previous
//
#include <hip/hip_runtime.h>

#define NN 50000
#define DD 128
#define NB 196          // ceil(50000/256)
#define PAD 16          // one counter per 64B line

typedef __attribute__((ext_vector_type(8))) short bf16x8;
typedef __attribute__((ext_vector_type(4))) float f32x4;

static __device__ __forceinline__ unsigned short f2bf(float x) {
    unsigned int u = __float_as_uint(x);
    unsigned int r = (u + 0x7fffu + ((u >> 16) & 1u)) >> 16;
    return (unsigned short)r;
}

// XOR-swizzle for 256B-row LDS tiles (row = byte>>8)
static __device__ __forceinline__ int swz(int byte) {
    return byte ^ (((byte >> 8) & 7) << 4);
}

// ---------- zero padded counters (3.2MB) + one-time Wt build ----------
__global__ void __launch_bounds__(256) zero_wt_kernel(
    int* __restrict__ pad, const float* __restrict__ W, unsigned short* __restrict__ Wt)
{
    if (blockIdx.x == 0) {
        for (int idx = threadIdx.x; idx < DD * DD; idx += 256) {
            int k = idx >> 7;
            int j = idx & 127;
            Wt[j * DD + k] = f2bf(W[idx]);
        }
    }
    int i = blockIdx.x * 256 + threadIdx.x;
    const int total = NN * PAD / 4;   // uint4 count = 200000
    if (i < total) {
        reinterpret_cast<uint4*>(pad)[i] = make_uint4(0u, 0u, 0u, 0u);
    }
}

// ---------- ticket pass: one spread atomic per edge ----------
__global__ void __launch_bounds__(256) ticket_kernel(
    const int* __restrict__ row, int* __restrict__ pad,
    unsigned short* __restrict__ tick, int E)
{
    int e = blockIdx.x * 256 + threadIdx.x;
    if (e < E) {
        int r = row[e];
        int t = atomicAdd(&pad[r * PAD], 1);
        tick[e] = (unsigned short)t;
    }
}

// ---------- hierarchical scan over padded counters -> dense counts + start wptr ----------
__global__ void __launch_bounds__(256) scan_local_kernel(
    const int* __restrict__ pad, int* __restrict__ counts,
    int* __restrict__ wptr, int* __restrict__ bsum)
{
    __shared__ int s[256];
    int tid = threadIdx.x;
    int i = blockIdx.x * 256 + tid;
    int v = (i < NN) ? pad[i * PAD] : 0;
    s[tid] = v;
    __syncthreads();
    #pragma unroll
    for (int d = 1; d < 256; d <<= 1) {
        int t = (tid >= d) ? s[tid - d] : 0;
        __syncthreads();
        s[tid] += t;
        __syncthreads();
    }
    if (i < NN) {
        counts[i] = v;
        wptr[i] = s[tid] - v;        // exclusive within chunk
    }
    if (tid == 255) bsum[blockIdx.x] = s[255];
}

// each block reduces bsum[0..blockIdx) and adds the prefix to its wptr chunk
__global__ void __launch_bounds__(256) scan_merge_add_kernel(
    int* __restrict__ wptr, const int* __restrict__ bsum)
{
    __shared__ int s[256];
    int tid = threadIdx.x;
    int b = blockIdx.x;
    s[tid] = (tid < b && tid < NB) ? bsum[tid] : 0;
    __syncthreads();
    #pragma unroll
    for (int d = 128; d > 0; d >>= 1) {
        if (tid < d) s[tid] += s[tid + d];
        __syncthreads();
    }
    int prefix = s[0];
    int i = b * 256 + tid;
    if (i < NN) wptr[i] += prefix;
}

// ---------- placement pass: no atomics ----------
__global__ void __launch_bounds__(256) place_kernel(
    const int* __restrict__ row, const int* __restrict__ col,
    const int* __restrict__ wptr, const unsigned short* __restrict__ tick,
    unsigned short* __restrict__ edge_col, int E)
{
    int e = blockIdx.x * 256 + threadIdx.x;
    if (e < E) {
        int r = row[e];
        edge_col[wptr[r] + (int)tick[e]] = (unsigned short)col[e];
    }
}

// ---------- y = bf16(x @ W): 64 rows/block, 4 waves, swizzled LDS ----------
__global__ void __launch_bounds__(256) gemm_xw_kernel(
    const float* __restrict__ x,
    const unsigned short* __restrict__ Wt,    // [j][k] bf16
    unsigned short* __restrict__ y)           // [NN][DD] bf16
{
    __shared__ unsigned short w_lds[DD * DD]; // 32KB, swizzled [j][k]
    __shared__ unsigned short a_lds[64 * DD]; // 16KB, swizzled [r][k]

    const int tid = threadIdx.x;
    const int i0 = blockIdx.x * 64;

    {
        const uint4* src = reinterpret_cast<const uint4*>(Wt);
        #pragma unroll
        for (int it = 0; it < 8; ++it) {
            int idx = tid + it * 256;
            uint4 v = src[idx];
            *reinterpret_cast<uint4*>((char*)w_lds + swz(idx * 16)) = v;
        }
    }
    #pragma unroll
    for (int it = 0; it < 8; ++it) {
        int idx = tid + it * 256;
        int r = idx >> 5;
        int c4 = idx & 31;
        int grow = i0 + r;
        float4 v = make_float4(0.f, 0.f, 0.f, 0.f);
        if (grow < NN) v = reinterpret_cast<const float4*>(x + (size_t)grow * DD)[c4];
        ushort4 o;
        o.x = f2bf(v.x); o.y = f2bf(v.y); o.z = f2bf(v.z); o.w = f2bf(v.w);
        *reinterpret_cast<ushort4*>((char*)a_lds + swz(r * 256 + c4 * 8)) = o;
    }
    __syncthreads();

    const int wave = tid >> 6;
    const int l64 = tid & 63;
    const int lrow = l64 & 15;
    const int kgrp = l64 >> 4;

    bf16x8 afrag[4];
    #pragma unroll
    for (int s = 0; s < 4; ++s) {
        int byte = (wave * 16 + lrow) * 256 + (s * 32 + kgrp * 8) * 2;
        afrag[s] = *reinterpret_cast<const bf16x8*>((char*)a_lds + swz(byte));
    }

    f32x4 acc[8];
    #pragma unroll
    for (int t = 0; t < 8; ++t) acc[t] = (f32x4){0.f, 0.f, 0.f, 0.f};

    #pragma unroll
    for (int t = 0; t < 8; ++t) {
        #pragma unroll
        for (int s = 0; s < 4; ++s) {
            int byte = (t * 16 + lrow) * 256 + (s * 32 + kgrp * 8) * 2;
            bf16x8 bfrag = *reinterpret_cast<const bf16x8*>((char*)w_lds + swz(byte));
            acc[t] = __builtin_amdgcn_mfma_f32_16x16x32_bf16(afrag[s], bfrag, acc[t], 0, 0, 0);
        }
    }
    __syncthreads();

    // D layout: col = lane&15, row = (lane>>4)*4 + reg  [m89-verified]
    #pragma unroll
    for (int t = 0; t < 8; ++t) {
        #pragma unroll
        for (int r = 0; r < 4; ++r) {
            int lr = wave * 16 + kgrp * 4 + r;
            int byte = lr * 256 + (t * 16 + lrow) * 2;
            *reinterpret_cast<unsigned short*>((char*)a_lds + swz(byte)) = f2bf(acc[t][r]);
        }
    }
    __syncthreads();

    {
        uint4* dst = reinterpret_cast<uint4*>(y) + (size_t)i0 * 16;
        #pragma unroll
        for (int it = 0; it < 4; ++it) {
            int idx = tid + it * 256;
            if (i0 + (idx >> 4) < NN) {
                uint4 v = *reinterpret_cast<const uint4*>((char*)a_lds + swz(idx * 16));
                dst[idx] = v;
            }
        }
    }
}

// ---------- gather from y + mean + bias + ReLU -> out (no LDS) ----------
__global__ void __launch_bounds__(256) gather_out_kernel(
    const unsigned short* __restrict__ y,
    const int* __restrict__ wptr, const int* __restrict__ counts,
    const unsigned short* __restrict__ edge_col,
    const float* __restrict__ bias,
    float* __restrict__ out)
{
    int node = blockIdx.x * 8 + (threadIdx.x >> 5);
    int lane = threadIdx.x & 31;
    float4 bb = reinterpret_cast<const float4*>(bias)[lane];
    if (node >= NN) return;
    int cnt = counts[node];
    int start = wptr[node];
    int end = start + cnt;
    float4 acc = make_float4(0.f, 0.f, 0.f, 0.f);
    for (int base = start; base < end; base += 32) {
        int cl = (base + lane < end) ? (int)edge_col[base + lane] : 0;
        int m = min(32, end - base);
        #pragma unroll 2
        for (int ii = 0; ii < m; ++ii) {
            int c = __shfl(cl, ii, 32);
            uint2 u = reinterpret_cast<const uint2*>(y + (size_t)c * DD)[lane];
            acc.x += __uint_as_float(u.x << 16);
            acc.y += __uint_as_float(u.x & 0xffff0000u);
            acc.z += __uint_as_float(u.y << 16);
            acc.w += __uint_as_float(u.y & 0xffff0000u);
        }
    }
    float inv = 1.0f / fmaxf((float)cnt, 1.0f);
    float4 o;
    o.x = fmaxf(acc.x * inv + bb.x, 0.f);
    o.y = fmaxf(acc.y * inv + bb.y, 0.f);
    o.z = fmaxf(acc.z * inv + bb.z, 0.f);
    o.w = fmaxf(acc.w * inv + bb.w, 0.f);
    reinterpret_cast<float4*>(out + (size_t)node * DD)[lane] = o;
}

// ---------- fallback path (ws too small): atomic scatter + f32-staged gemm ----------
__global__ void __launch_bounds__(256) wt_only_kernel(
    const float* __restrict__ W, unsigned short* __restrict__ Wt)
{
    for (int idx = threadIdx.x; idx < DD * DD; idx += 256) {
        int k = idx >> 7;
        int j = idx & 127;
        Wt[j * DD + k] = f2bf(W[idx]);
    }
}

__global__ void __launch_bounds__(256) scatter_atomic_kernel(
    const float* __restrict__ x,
    const int* __restrict__ row, const int* __restrict__ col,
    float* __restrict__ agg, int* __restrict__ counts, int E)
{
    int gid = blockIdx.x * blockDim.x + threadIdx.x;
    int group = gid >> 5;
    int lane = threadIdx.x & 31;
    int ngroups = (gridDim.x * blockDim.x) >> 5;
    for (int e = group; e < E; e += ngroups) {
        int r = row[e];
        int c = col[e];
        float4 v = reinterpret_cast<const float4*>(x + (size_t)c * DD)[lane];
        float* dst = agg + (size_t)r * DD + lane * 4;
        unsafeAtomicAdd(dst + 0, v.x);
        unsafeAtomicAdd(dst + 1, v.y);
        unsafeAtomicAdd(dst + 2, v.z);
        unsafeAtomicAdd(dst + 3, v.w);
        if (lane == 0) atomicAdd(counts + r, 1);
    }
}

__global__ void __launch_bounds__(256) gemm_fb_kernel(
    const float* __restrict__ agg,
    const int* __restrict__ counts,
    const unsigned short* __restrict__ Wt,
    const float* __restrict__ bias,
    float* __restrict__ out)
{
    __shared__ unsigned short w_lds[DD * DD];
    __shared__ unsigned short a_lds[64 * DD];
    __shared__ float b_lds[DD];

    const int tid = threadIdx.x;
    const int i0 = blockIdx.x * 64;

    {
        const uint4* src = reinterpret_cast<const uint4*>(Wt);
        #pragma unroll
        for (int it = 0; it < 8; ++it) {
            int idx = tid + it * 256;
            *reinterpret_cast<uint4*>((char*)w_lds + swz(idx * 16)) = src[idx];
        }
    }
    if (tid < DD) b_lds[tid] = bias[tid];

    #pragma unroll
    for (int it = 0; it < 8; ++it) {
        int idx = tid + it * 256;
        int r = idx >> 5;
        int c4 = idx & 31;
        int grow = i0 + r;
        float4 v = make_float4(0.f, 0.f, 0.f, 0.f);
        float inv = 0.f;
        if (grow < NN) {
            v = reinterpret_cast<const float4*>(agg + (size_t)grow * DD)[c4];
            inv = 1.0f / fmaxf((float)counts[grow], 1.0f);
        }
        ushort4 o;
        o.x = f2bf(v.x * inv); o.y = f2bf(v.y * inv);
        o.z = f2bf(v.z * inv); o.w = f2bf(v.w * inv);
        *reinterpret_cast<ushort4*>((char*)a_lds + swz(r * 256 + c4 * 8)) = o;
    }
    __syncthreads();

    const int wave = tid >> 6;
    const int l64 = tid & 63;
    const int lrow = l64 & 15;
    const int kgrp = l64 >> 4;

    bf16x8 afrag[4];
    #pragma unroll
    for (int s = 0; s < 4; ++s) {
        int byte = (wave * 16 + lrow) * 256 + (s * 32 + kgrp * 8) * 2;
        afrag[s] = *reinterpret_cast<const bf16x8*>((char*)a_lds + swz(byte));
    }

    f32x4 acc[8];
    #pragma unroll
    for (int t = 0; t < 8; ++t) acc[t] = (f32x4){0.f, 0.f, 0.f, 0.f};

    #pragma unroll
    for (int t = 0; t < 8; ++t) {
        #pragma unroll
        for (int s = 0; s < 4; ++s) {
            int byte = (t * 16 + lrow) * 256 + (s * 32 + kgrp * 8) * 2;
            bf16x8 bfrag = *reinterpret_cast<const bf16x8*>((char*)w_lds + swz(byte));
            acc[t] = __builtin_amdgcn_mfma_f32_16x16x32_bf16(afrag[s], bfrag, acc[t], 0, 0, 0);
        }
    }

    #pragma unroll
    for (int t = 0; t < 8; ++t) {
        int colj = t * 16 + lrow;
        float bbv = b_lds[colj];
        #pragma unroll
        for (int r = 0; r < 4; ++r) {
            int grow = i0 + wave * 16 + kgrp * 4 + r;
            if (grow < NN) {
                out[(size_t)grow * DD + colj] = fmaxf(acc[t][r] + bbv, 0.f);
            }
        }
    }
}

extern "C" void kernel_launch(void* const* d_in, const int* in_sizes, int n_in,
                              void* d_out, int out_size, void* d_ws, size_t ws_size,
                              hipStream_t stream) {
    const float* x  = (const float*)d_in[0];
    const int* ei   = (const int*)d_in[1];
    const float* W  = (const float*)d_in[2];
    const float* b  = (const float*)d_in[3];
    float* out      = (float*)d_out;

    const int E = in_sizes[1] / 2;
    const int* row = ei;
    const int* col = ei + E;

    // ws layout (16B-aligned)
    char* wsc = (char*)d_ws;
    int* pad                 = (int*)(wsc + 0);                 // 3,200,000 B (50000 * 64B)
    int* wptr                = (int*)(wsc + 3200000);           // 200,704 B
    int* counts              = (int*)(wsc + 3400704);           // 200,704 B
    int* bsum                = (int*)(wsc + 3601408);           // 1,024 B
    unsigned short* tick     = (unsigned short*)(wsc + 3602432);   // 1,280,000 B
    unsigned short* edge_col = (unsigned short*)(wsc + 4882432);   // 1,280,000 B
    unsigned short* Wt       = (unsigned short*)(wsc + 6162432);   // 32,768 B
    unsigned short* y        = (unsigned short*)(wsc + 6195200);   // 12,800,000 B
    const size_t WS_NEED = 18995200;

    const int EB = (E + 255) / 256;   // 2500

    if (ws_size >= WS_NEED) {
        zero_wt_kernel<<<800, 256, 0, stream>>>(pad, W, Wt);
        ticket_kernel<<<EB, 256, 0, stream>>>(row, pad, tick, E);
        scan_local_kernel<<<NB, 256, 0, stream>>>(pad, counts, wptr, bsum);
        scan_merge_add_kernel<<<NB, 256, 0, stream>>>(wptr, bsum);
        place_kernel<<<EB, 256, 0, stream>>>(row, col, wptr, tick, edge_col, E);
        gemm_xw_kernel<<<(NN + 63) / 64, 256, 0, stream>>>(x, Wt, y);
        gather_out_kernel<<<(NN + 7) / 8, 256, 0, stream>>>(y, wptr, counts, edge_col, b, out);
    } else {
        int* fc = (int*)d_ws;
        unsigned short* fWt = (unsigned short*)(wsc + 200704);
        hipMemsetAsync(d_out, 0, (size_t)NN * DD * sizeof(float), stream);
        hipMemsetAsync(fc, 0, (size_t)NN * sizeof(int), stream);
        wt_only_kernel<<<1, 256, 0, stream>>>(W, fWt);
        scatter_atomic_kernel<<<2048, 256, 0, stream>>>(x, row, col, out, fc, E);
        gemm_fb_kernel<<<(NN + 63) / 64, 256, 0, stream>>>(out, fc, fWt, b, out);
    }
}

// Round 7
// 100.486 us; speedup vs baseline: 2.1663x; 1.0826x over previous
//
#include <hip/hip_runtime.h>

#define NN 50000
#define DD 128
#define NB 196          // ceil(50000/256)
#define PAD 16          // one counter per 64B line
#define GEMM_BLOCKS 782 // ceil(50000/64)

typedef __attribute__((ext_vector_type(8))) short bf16x8;
typedef __attribute__((ext_vector_type(4))) float f32x4;

static __device__ __forceinline__ unsigned short f2bf(float x) {
    unsigned int u = __float_as_uint(x);
    unsigned int r = (u + 0x7fffu + ((u >> 16) & 1u)) >> 16;
    return (unsigned short)r;
}

// XOR-swizzle for 256B-row LDS tiles (row = byte>>8)
static __device__ __forceinline__ int swz(int byte) {
    return byte ^ (((byte >> 8) & 7) << 4);
}

// ---------- zero padded counters (3.2MB) + one-time Wt build ----------
__global__ void __launch_bounds__(256) zero_wt_kernel(
    int* __restrict__ pad, const float* __restrict__ W, unsigned short* __restrict__ Wt)
{
    if (blockIdx.x == 0) {
        for (int idx = threadIdx.x; idx < DD * DD; idx += 256) {
            int k = idx >> 7;
            int j = idx & 127;
            Wt[j * DD + k] = f2bf(W[idx]);
        }
    }
    int i = blockIdx.x * 256 + threadIdx.x;
    const int total = NN * PAD / 4;   // uint4 count = 200000
    if (i < total) {
        reinterpret_cast<uint4*>(pad)[i] = make_uint4(0u, 0u, 0u, 0u);
    }
}

// ---------- mega: blocks [0,GEMM_BLOCKS) do y=bf16(x@W); rest do ticket pass ----------
__global__ void __launch_bounds__(256) mega_kernel(
    const float* __restrict__ x,
    const unsigned short* __restrict__ Wt,    // [j][k] bf16
    unsigned short* __restrict__ y,           // [NN][DD] bf16
    const int* __restrict__ row, int* __restrict__ pad,
    unsigned short* __restrict__ tick, int E)
{
    __shared__ unsigned short w_lds[DD * DD]; // 32KB, swizzled [j][k]
    __shared__ unsigned short a_lds[64 * DD]; // 16KB, swizzled [r][k]

    const int tid = threadIdx.x;
    const int bid = blockIdx.x;

    if (bid >= GEMM_BLOCKS) {
        // ---- ticket: one spread atomic per edge ----
        int e = (bid - GEMM_BLOCKS) * 256 + tid;
        if (e < E) {
            int r = row[e];
            int t = atomicAdd(&pad[r * PAD], 1);
            tick[e] = (unsigned short)t;
        }
        return;
    }

    // ---- gemm path ----
    const int i0 = bid * 64;
    {
        const uint4* src = reinterpret_cast<const uint4*>(Wt);
        #pragma unroll
        for (int it = 0; it < 8; ++it) {
            int idx = tid + it * 256;
            uint4 v = src[idx];
            *reinterpret_cast<uint4*>((char*)w_lds + swz(idx * 16)) = v;
        }
    }
    #pragma unroll
    for (int it = 0; it < 8; ++it) {
        int idx = tid + it * 256;
        int r = idx >> 5;
        int c4 = idx & 31;
        int grow = i0 + r;
        float4 v = make_float4(0.f, 0.f, 0.f, 0.f);
        if (grow < NN) v = reinterpret_cast<const float4*>(x + (size_t)grow * DD)[c4];
        ushort4 o;
        o.x = f2bf(v.x); o.y = f2bf(v.y); o.z = f2bf(v.z); o.w = f2bf(v.w);
        *reinterpret_cast<ushort4*>((char*)a_lds + swz(r * 256 + c4 * 8)) = o;
    }
    __syncthreads();

    const int wave = tid >> 6;
    const int l64 = tid & 63;
    const int lrow = l64 & 15;
    const int kgrp = l64 >> 4;

    bf16x8 afrag[4];
    #pragma unroll
    for (int s = 0; s < 4; ++s) {
        int byte = (wave * 16 + lrow) * 256 + (s * 32 + kgrp * 8) * 2;
        afrag[s] = *reinterpret_cast<const bf16x8*>((char*)a_lds + swz(byte));
    }

    f32x4 acc[8];
    #pragma unroll
    for (int t = 0; t < 8; ++t) acc[t] = (f32x4){0.f, 0.f, 0.f, 0.f};

    #pragma unroll
    for (int t = 0; t < 8; ++t) {
        #pragma unroll
        for (int s = 0; s < 4; ++s) {
            int byte = (t * 16 + lrow) * 256 + (s * 32 + kgrp * 8) * 2;
            bf16x8 bfrag = *reinterpret_cast<const bf16x8*>((char*)w_lds + swz(byte));
            acc[t] = __builtin_amdgcn_mfma_f32_16x16x32_bf16(afrag[s], bfrag, acc[t], 0, 0, 0);
        }
    }
    __syncthreads();

    // D layout: col = lane&15, row = (lane>>4)*4 + reg  [m89-verified]
    #pragma unroll
    for (int t = 0; t < 8; ++t) {
        #pragma unroll
        for (int r = 0; r < 4; ++r) {
            int lr = wave * 16 + kgrp * 4 + r;
            int byte = lr * 256 + (t * 16 + lrow) * 2;
            *reinterpret_cast<unsigned short*>((char*)a_lds + swz(byte)) = f2bf(acc[t][r]);
        }
    }
    __syncthreads();

    {
        uint4* dst = reinterpret_cast<uint4*>(y) + (size_t)i0 * 16;
        #pragma unroll
        for (int it = 0; it < 4; ++it) {
            int idx = tid + it * 256;
            if (i0 + (idx >> 4) < NN) {
                uint4 v = *reinterpret_cast<const uint4*>((char*)a_lds + swz(idx * 16));
                dst[idx] = v;
            }
        }
    }
}

// ---------- scan over padded counters -> dense counts + LOCAL exclusive wptr + bsum ----------
__global__ void __launch_bounds__(256) scan_local_kernel(
    const int* __restrict__ pad, int* __restrict__ counts,
    int* __restrict__ wloc, int* __restrict__ bsum)
{
    __shared__ int s[256];
    int tid = threadIdx.x;
    int i = blockIdx.x * 256 + tid;
    int v = (i < NN) ? pad[i * PAD] : 0;
    s[tid] = v;
    __syncthreads();
    #pragma unroll
    for (int d = 1; d < 256; d <<= 1) {
        int t = (tid >= d) ? s[tid - d] : 0;
        __syncthreads();
        s[tid] += t;
        __syncthreads();
    }
    if (i < NN) {
        counts[i] = v;
        wloc[i] = s[tid] - v;        // exclusive within chunk
    }
    if (tid == 255) bsum[blockIdx.x] = s[255];
}

// ---------- 1-block exclusive scan of the NB block sums (in place) ----------
__global__ void __launch_bounds__(256) prefix_kernel(int* __restrict__ bsum)
{
    __shared__ int s[256];
    int tid = threadIdx.x;
    int v = (tid < NB) ? bsum[tid] : 0;
    s[tid] = v;
    __syncthreads();
    #pragma unroll
    for (int d = 1; d < 256; d <<= 1) {
        int t = (tid >= d) ? s[tid - d] : 0;
        __syncthreads();
        s[tid] += t;
        __syncthreads();
    }
    if (tid < NB) bsum[tid] = s[tid] - v;   // exclusive
}

// ---------- placement pass: no atomics ----------
__global__ void __launch_bounds__(256) place_kernel(
    const int* __restrict__ row, const int* __restrict__ col,
    const int* __restrict__ wloc, const int* __restrict__ prefix,
    const unsigned short* __restrict__ tick,
    unsigned short* __restrict__ edge_col, int E)
{
    int e = blockIdx.x * 256 + threadIdx.x;
    if (e < E) {
        int r = row[e];
        int start = wloc[r] + prefix[r >> 8];
        edge_col[start + (int)tick[e]] = (unsigned short)col[e];
    }
}

// ---------- gather from y + mean + bias + ReLU -> out ----------
// 32-lane group per node; 16 lanes cover one 256B y-row (uint4), 2 edges in flight.
__global__ void __launch_bounds__(256) gather_out_kernel(
    const unsigned short* __restrict__ y,
    const int* __restrict__ wloc, const int* __restrict__ prefix,
    const int* __restrict__ counts,
    const unsigned short* __restrict__ edge_col,
    const float* __restrict__ bias,
    float* __restrict__ out)
{
    int node = blockIdx.x * 8 + (threadIdx.x >> 5);
    int lane = threadIdx.x & 31;
    int half = lane >> 4;       // 0: even edges, 1: odd edges
    int l16 = lane & 15;        // covers y-row elements [8*l16, 8*l16+8)
    if (node >= NN) return;
    int cnt = counts[node];
    int start = wloc[node] + prefix[node >> 8];
    int end = start + cnt;

    float acc[8];
    #pragma unroll
    for (int j = 0; j < 8; ++j) acc[j] = 0.f;

    for (int base = start; base < end; base += 32) {
        int cl = (base + lane < end) ? (int)edge_col[base + lane] : 0;
        int m = min(32, end - base);
        for (int ii = 0; ii < m; ii += 2) {
            int src = ii + half;
            int c = __shfl(cl, src, 32);
            if (src < m) {
                uint4 u = reinterpret_cast<const uint4*>(y + (size_t)c * DD)[l16];
                acc[0] += __uint_as_float(u.x << 16);
                acc[1] += __uint_as_float(u.x & 0xffff0000u);
                acc[2] += __uint_as_float(u.y << 16);
                acc[3] += __uint_as_float(u.y & 0xffff0000u);
                acc[4] += __uint_as_float(u.z << 16);
                acc[5] += __uint_as_float(u.z & 0xffff0000u);
                acc[6] += __uint_as_float(u.w << 16);
                acc[7] += __uint_as_float(u.w & 0xffff0000u);
            }
        }
    }
    // merge the two halves: lanes l and l^16 hold partial sums for the same cols
    #pragma unroll
    for (int j = 0; j < 8; ++j) acc[j] += __shfl_xor(acc[j], 16, 32);

    float inv = 1.0f / fmaxf((float)cnt, 1.0f);
    float4 bb = reinterpret_cast<const float4*>(bias)[2 * l16 + half];
    float4 o;
    o.x = fmaxf(acc[4 * half + 0] * inv + bb.x, 0.f);
    o.y = fmaxf(acc[4 * half + 1] * inv + bb.y, 0.f);
    o.z = fmaxf(acc[4 * half + 2] * inv + bb.z, 0.f);
    o.w = fmaxf(acc[4 * half + 3] * inv + bb.w, 0.f);
    reinterpret_cast<float4*>(out + (size_t)node * DD)[2 * l16 + half] = o;
}

// ---------- fallback path (ws too small): atomic scatter + f32-staged gemm ----------
__global__ void __launch_bounds__(256) wt_only_kernel(
    const float* __restrict__ W, unsigned short* __restrict__ Wt)
{
    for (int idx = threadIdx.x; idx < DD * DD; idx += 256) {
        int k = idx >> 7;
        int j = idx & 127;
        Wt[j * DD + k] = f2bf(W[idx]);
    }
}

__global__ void __launch_bounds__(256) scatter_atomic_kernel(
    const float* __restrict__ x,
    const int* __restrict__ row, const int* __restrict__ col,
    float* __restrict__ agg, int* __restrict__ counts, int E)
{
    int gid = blockIdx.x * blockDim.x + threadIdx.x;
    int group = gid >> 5;
    int lane = threadIdx.x & 31;
    int ngroups = (gridDim.x * blockDim.x) >> 5;
    for (int e = group; e < E; e += ngroups) {
        int r = row[e];
        int c = col[e];
        float4 v = reinterpret_cast<const float4*>(x + (size_t)c * DD)[lane];
        float* dst = agg + (size_t)r * DD + lane * 4;
        unsafeAtomicAdd(dst + 0, v.x);
        unsafeAtomicAdd(dst + 1, v.y);
        unsafeAtomicAdd(dst + 2, v.z);
        unsafeAtomicAdd(dst + 3, v.w);
        if (lane == 0) atomicAdd(counts + r, 1);
    }
}

__global__ void __launch_bounds__(256) gemm_fb_kernel(
    const float* __restrict__ agg,
    const int* __restrict__ counts,
    const unsigned short* __restrict__ Wt,
    const float* __restrict__ bias,
    float* __restrict__ out)
{
    __shared__ unsigned short w_lds[DD * DD];
    __shared__ unsigned short a_lds[64 * DD];
    __shared__ float b_lds[DD];

    const int tid = threadIdx.x;
    const int i0 = blockIdx.x * 64;

    {
        const uint4* src = reinterpret_cast<const uint4*>(Wt);
        #pragma unroll
        for (int it = 0; it < 8; ++it) {
            int idx = tid + it * 256;
            *reinterpret_cast<uint4*>((char*)w_lds + swz(idx * 16)) = src[idx];
        }
    }
    if (tid < DD) b_lds[tid] = bias[tid];

    #pragma unroll
    for (int it = 0; it < 8; ++it) {
        int idx = tid + it * 256;
        int r = idx >> 5;
        int c4 = idx & 31;
        int grow = i0 + r;
        float4 v = make_float4(0.f, 0.f, 0.f, 0.f);
        float inv = 0.f;
        if (grow < NN) {
            v = reinterpret_cast<const float4*>(agg + (size_t)grow * DD)[c4];
            inv = 1.0f / fmaxf((float)counts[grow], 1.0f);
        }
        ushort4 o;
        o.x = f2bf(v.x * inv); o.y = f2bf(v.y * inv);
        o.z = f2bf(v.z * inv); o.w = f2bf(v.w * inv);
        *reinterpret_cast<ushort4*>((char*)a_lds + swz(r * 256 + c4 * 8)) = o;
    }
    __syncthreads();

    const int wave = tid >> 6;
    const int l64 = tid & 63;
    const int lrow = l64 & 15;
    const int kgrp = l64 >> 4;

    bf16x8 afrag[4];
    #pragma unroll
    for (int s = 0; s < 4; ++s) {
        int byte = (wave * 16 + lrow) * 256 + (s * 32 + kgrp * 8) * 2;
        afrag[s] = *reinterpret_cast<const bf16x8*>((char*)a_lds + swz(byte));
    }

    f32x4 acc[8];
    #pragma unroll
    for (int t = 0; t < 8; ++t) acc[t] = (f32x4){0.f, 0.f, 0.f, 0.f};

    #pragma unroll
    for (int t = 0; t < 8; ++t) {
        #pragma unroll
        for (int s = 0; s < 4; ++s) {
            int byte = (t * 16 + lrow) * 256 + (s * 32 + kgrp * 8) * 2;
            bf16x8 bfrag = *reinterpret_cast<const bf16x8*>((char*)w_lds + swz(byte));
            acc[t] = __builtin_amdgcn_mfma_f32_16x16x32_bf16(afrag[s], bfrag, acc[t], 0, 0, 0);
        }
    }

    #pragma unroll
    for (int t = 0; t < 8; ++t) {
        int colj = t * 16 + lrow;
        float bbv = b_lds[colj];
        #pragma unroll
        for (int r = 0; r < 4; ++r) {
            int grow = i0 + wave * 16 + kgrp * 4 + r;
            if (grow < NN) {
                out[(size_t)grow * DD + colj] = fmaxf(acc[t][r] + bbv, 0.f);
            }
        }
    }
}

extern "C" void kernel_launch(void* const* d_in, const int* in_sizes, int n_in,
                              void* d_out, int out_size, void* d_ws, size_t ws_size,
                              hipStream_t stream) {
    const float* x  = (const float*)d_in[0];
    const int* ei   = (const int*)d_in[1];
    const float* W  = (const float*)d_in[2];
    const float* b  = (const float*)d_in[3];
    float* out      = (float*)d_out;

    const int E = in_sizes[1] / 2;
    const int* row = ei;
    const int* col = ei + E;

    // ws layout (16B-aligned)
    char* wsc = (char*)d_ws;
    int* pad                 = (int*)(wsc + 0);                 // 3,200,000 B (50000 * 64B)
    int* wloc                = (int*)(wsc + 3200000);           // 200,704 B
    int* counts              = (int*)(wsc + 3400704);           // 200,704 B
    int* bsum                = (int*)(wsc + 3601408);           // 1,024 B
    unsigned short* tick     = (unsigned short*)(wsc + 3602432);   // 1,280,000 B
    unsigned short* edge_col = (unsigned short*)(wsc + 4882432);   // 1,280,000 B
    unsigned short* Wt       = (unsigned short*)(wsc + 6162432);   // 32,768 B
    unsigned short* y        = (unsigned short*)(wsc + 6195200);   // 12,800,000 B
    const size_t WS_NEED = 18995200;

    const int EB = (E + 255) / 256;   // 2500

    if (ws_size >= WS_NEED) {
        zero_wt_kernel<<<800, 256, 0, stream>>>(pad, W, Wt);
        mega_kernel<<<GEMM_BLOCKS + EB, 256, 0, stream>>>(x, Wt, y, row, pad, tick, E);
        scan_local_kernel<<<NB, 256, 0, stream>>>(pad, counts, wloc, bsum);
        prefix_kernel<<<1, 256, 0, stream>>>(bsum);
        place_kernel<<<EB, 256, 0, stream>>>(row, col, wloc, bsum, tick, edge_col, E);
        gather_out_kernel<<<(NN + 7) / 8, 256, 0, stream>>>(y, wloc, bsum, counts, edge_col, b, out);
    } else {
        int* fc = (int*)d_ws;
        unsigned short* fWt = (unsigned short*)(wsc + 200704);
        hipMemsetAsync(d_out, 0, (size_t)NN * DD * sizeof(float), stream);
        hipMemsetAsync(fc, 0, (size_t)NN * sizeof(int), stream);
        wt_only_kernel<<<1, 256, 0, stream>>>(W, fWt);
        scatter_atomic_kernel<<<2048, 256, 0, stream>>>(x, row, col, out, fc, E);
        gemm_fb_kernel<<<(NN + 63) / 64, 256, 0, stream>>>(out, fc, fWt, b, out);
    }
}